// Round 14
// baseline (386.601 us; speedup 1.0000x reference)
//
#include <hip/hip_runtime.h>
#include <stdint.h>

// RBF kernel regression: out = exp(-gamma*d2(Xq,Xt)) @ alpha
// out[m] = ea[m] * sum_n w[n] * 2^( S[m][n] ),  S = (2*gamma*log2e*Xq).Xt^T
//
// R14: switch MFMA shape 16x16x32 -> 32x32x16 (2382 vs 2075 TF ubench, -17%
// matrix time; half the MFMA issue slots). R6-R13 fit: main ~= SUM(matrix
// 13.5, L1 13.1, trans/VALU ~6) us — pipes sum, scheduling tweaks neutral
// (R10/R11/R13), so cut the largest term. B bytes & exp count unchanged.
// A/B operand k-layout errors cancel (same packing both sides -> k-bijection
// invariant); C/D layout is the MEASURED m74 map: col=lane&31,
// row=(reg&3)+8*(reg>>2)+4*(lane>>5). B in 3-rotating quarter-K chunks
// (48 regs) keeps total ~250 <= 256 (no spill; WRITE_SIZE is the canary).
// Locked: bf16 (fp8 fails calibration), 64 rows/wave, 512 blocks, regular
// loads not global_load_lds (R1-R5: DMA bypassed L2), no per-step barriers
// (R9), w in LDS (lgkm-decoupled, R7 lesson).

#define MM 8192
#define NN 8192
#define DD 256
#define GAMMA (1.0f/256.0f)
#define LOG2E 1.44269504088896340736f
#define SCALE_A (2.0f*GAMMA*LOG2E)
#define NEG_G_LOG2E (-GAMMA*LOG2E)

#define NSPLIT 16
#define NPB (NN/NSPLIT)     // 512 cols per block
#define NT_PER (NPB/32)     // 16 column-tiles of 32
#define NCHUNK (NT_PER*4)   // 64 quarter-K chunks per block pass

typedef __bf16 bf16x8 __attribute__((ext_vector_type(8)));
typedef float  f32x16 __attribute__((ext_vector_type(16)));

// ws: [0,4MB) A frag-linear (32-row tiles); [4MB,8MB) B frag-linear;
//     [8MB,+32K) w; [+32K] ea; [+64K] part[16][8192] f32
#define A_OFF  ((size_t)0)
#define B_OFF  ((size_t)4 << 20)
#define W_OFF  ((size_t)8 << 20)
#define EA_OFF (((size_t)8 << 20) + 32768)
#define PART_OFF (((size_t)8 << 20) + 65536)

__device__ __forceinline__ unsigned short f2bf(float f) {  // RNE f32->bf16
  union { float f; uint32_t u; } x; x.f = f;
  uint32_t u = x.u;
  u += 0x7FFFu + ((u >> 16) & 1u);
  return (unsigned short)(u >> 16);
}
__device__ __forceinline__ uint32_t pack2(float a, float b) {
  return (uint32_t)f2bf(a) | ((uint32_t)f2bf(b) << 16);
}

// 32-row/col tile t, k-step s (K=16 each), lane l: the 16 B at
// dst + t*16384 + s*1024 + l*16 hold row/col n = t*32+(l&31),
// k = s*16 + (l>>5)*8 .. +8  — the mfma_32x32x16 A/B operand layout
// (k-convention shared by A and B, so any k-permutation error cancels).
__global__ __launch_bounds__(256) void prep_kernel(
    const float* __restrict__ Xq, const float* __restrict__ Xt,
    const float* __restrict__ alpha,
    char* __restrict__ Amat, char* __restrict__ Bmat,
    float* __restrict__ w, float* __restrict__ ea)
{
  const int lane = threadIdx.x & 63;
  const int gw = blockIdx.x * 4 + (threadIdx.x >> 6);  // 0..511
  const bool isA = gw < 256;
  const int t = isA ? gw : gw - 256;
  const float* __restrict__ src = isA ? Xq : Xt;
  char* __restrict__ dst = isA ? Amat : Bmat;
  const float sc = isA ? SCALE_A : 1.0f;
  const int r = t * 32 + (lane & 31);
  const int h = lane >> 5;
  float ss = 0.f;
#pragma unroll
  for (int s = 0; s < 16; ++s) {
    const float* p = src + (size_t)r * DD + s * 16 + h * 8;
    const float4 f0 = *(const float4*)p;
    const float4 f1 = *(const float4*)(p + 4);
    ss += f0.x*f0.x + f0.y*f0.y + f0.z*f0.z + f0.w*f0.w
        + f1.x*f1.x + f1.y*f1.y + f1.z*f1.z + f1.w*f1.w;
    uint4 pk;
    pk.x = pack2(f0.x * sc, f0.y * sc); pk.y = pack2(f0.z * sc, f0.w * sc);
    pk.z = pack2(f1.x * sc, f1.y * sc); pk.w = pack2(f1.z * sc, f1.w * sc);
    *(uint4*)(dst + (size_t)t * 16384 + s * 1024 + lane * 16) = pk;
  }
  ss += __shfl_xor(ss, 32, 64);   // combine the two k-halves of row r
  if (lane < 32) {
    if (isA) ea[r] = __builtin_amdgcn_exp2f(NEG_G_LOG2E * ss);
    else     w[r]  = alpha[r] * __builtin_amdgcn_exp2f(NEG_G_LOG2E * ss);
  }
}

__global__ __launch_bounds__(256, 2) void rbf_main(
    const char* __restrict__ Amat, const char* __restrict__ Bmat,
    const float* __restrict__ w, const float* __restrict__ ea,
    float* __restrict__ part)
{
  __shared__ float lds_w[NPB];   // 2 KB: the block's w slice (lgkm-only reads)
  const int tid  = threadIdx.x;
  const int wave = tid >> 6, lane = tid & 63;
  const int l32 = lane & 31, h = lane >> 5;

  // 512 blocks = 32 my x 16 nx; XCD b&7 gets 8 my x 8 nx
  const int b    = blockIdx.x;
  const int xcd  = b & 7, slot = b >> 3;             // slot 0..63
  const int my   = (xcd & 3) * 8 + (slot & 7);       // 0..31 (256 rows each)
  const int nx   = (xcd >> 2) * 8 + (slot >> 3);     // 0..15
  const int mt0    = my * 8 + wave * 2;              // 2 row-tiles of 32 = 64 rows/wave
  const int nt0    = nx * NT_PER;
  const int nbase0 = nx * NPB;

  // stage w slice to LDS (single barrier in the whole kernel)
  {
    const float2 wv2 = *(const float2*)(w + nbase0 + tid * 2);
    lds_w[tid * 2]     = wv2.x;
    lds_w[tid * 2 + 1] = wv2.y;
  }

  // A fragments register-resident for full K=256: 2 rt x 16 s x 4 = 128 regs
  bf16x8 afrag[2][16];
#pragma unroll
  for (int rt = 0; rt < 2; ++rt)
#pragma unroll
    for (int s = 0; s < 16; ++s) {
      union { uint4 u; bf16x8 v; } cv;
      cv.u = *(const uint4*)(Amat + (size_t)(mt0 + rt) * 16384 + s * 1024 + lane * 16);
      afrag[rt][s] = cv.v;
    }

  __syncthreads();   // lds_w ready

  float outacc[2][16];
#pragma unroll
  for (int rt = 0; rt < 2; ++rt)
#pragma unroll
    for (int i = 0; i < 16; ++i) outacc[rt][i] = 0.f;

  f32x16 acc[2];
  const f32x16 zero16 = {0,0,0,0,0,0,0,0,0,0,0,0,0,0,0,0};
  acc[0] = zero16; acc[1] = zero16;

  // B in quarter-K chunks (4 k-steps = 16 regs), rotating 3-buffer
  uint4 ch[3][4];
  auto loadChunk = [&](int slotIdx, int g) {      // g = global chunk id
    const int ct = g >> 2, c = g & 3;
    const char* base = Bmat + (size_t)(nt0 + ct) * 16384 + c * 4096 + (size_t)lane * 16;
#pragma unroll
    for (int q = 0; q < 4; ++q)
      ch[slotIdx][q] = *(const uint4*)(base + q * 1024);
  };
  auto mfmaChunk = [&](int slotIdx, int c) {      // c = chunk within tile
#pragma unroll
    for (int q = 0; q < 4; ++q) {
      const int s = c * 4 + q;
      union { uint4 u; bf16x8 v; } cv; cv.u = ch[slotIdx][q];
#pragma unroll
      for (int rt = 0; rt < 2; ++rt)
        acc[rt] = __builtin_amdgcn_mfma_f32_32x32x16_bf16(afrag[rt][s], cv.v, acc[rt], 0, 0, 0);
    }
  };
  auto epi = [&](int ct) {
    const float wv = lds_w[ct * 32 + l32];        // ds_read: lgkm only
#pragma unroll
    for (int rt = 0; rt < 2; ++rt) {
#pragma unroll
      for (int i = 0; i < 16; ++i)
        outacc[rt][i] += wv * __builtin_amdgcn_exp2f(acc[rt][i]);
      acc[rt] = zero16;
    }
  };

  loadChunk(0, 0);
  loadChunk(1, 1);
  for (int g = 0; g < NCHUNK; ++g) {
    mfmaChunk(g % 3, g & 3);
    if (g + 2 < NCHUNK) loadChunk((g + 2) % 3, g + 2);
    if ((g & 3) == 3) epi(g >> 2);
  }

  // reduce over the 32 columns (l32); C/D row = (i&3)+8*(i>>2)+4*h
#pragma unroll
  for (int rt = 0; rt < 2; ++rt)
#pragma unroll
    for (int i = 0; i < 16; ++i) {
      float v = outacc[rt][i];
      v += __shfl_xor(v, 1, 64);
      v += __shfl_xor(v, 2, 64);
      v += __shfl_xor(v, 4, 64);
      v += __shfl_xor(v, 8, 64);
      v += __shfl_xor(v, 16, 64);
      if (l32 == 0) {
        const int row = my * 256 + wave * 64 + rt * 32 + (i & 3) + 8 * (i >> 2) + 4 * h;
        part[(size_t)nx * MM + row] = ea[row] * v;
      }
    }
}

__global__ __launch_bounds__(256) void reduce_kernel(
    const float* __restrict__ part, float* __restrict__ out)
{
  const int row = blockIdx.x * 256 + threadIdx.x;
  float s = 0.f;
#pragma unroll
  for (int i = 0; i < NSPLIT; ++i) s += part[(size_t)i * MM + row];
  out[row] = s;
}

extern "C" void kernel_launch(void* const* d_in, const int* in_sizes, int n_in,
                              void* d_out, int out_size, void* d_ws, size_t ws_size,
                              hipStream_t stream) {
  const float* Xq    = (const float*)d_in[0];
  const float* Xt    = (const float*)d_in[1];
  const float* alpha = (const float*)d_in[2];
  float* out = (float*)d_out;
  char*  ws  = (char*)d_ws;

  char*  Amat = ws + A_OFF;
  char*  Bmat = ws + B_OFF;
  float* w    = (float*)(ws + W_OFF);
  float* ea   = (float*)(ws + EA_OFF);
  float* part = (float*)(ws + PART_OFF);

  hipLaunchKernelGGL(prep_kernel, dim3(128), dim3(256), 0, stream,
                     Xq, Xt, alpha, Amat, Bmat, w, ea);
  hipLaunchKernelGGL(rbf_main, dim3(512), dim3(256), 0, stream,
                     Amat, Bmat, w, ea, part);
  hipLaunchKernelGGL(reduce_kernel, dim3(MM / 256), dim3(256), 0, stream,
                     part, out);
}

// Round 15
// 113.063 us; speedup vs baseline: 3.4193x; 3.4193x over previous
//
#include <hip/hip_runtime.h>
#include <stdint.h>

// RBF kernel regression: out = exp(-gamma*d2(Xq,Xt)) @ alpha
// out[m] = ea[m] * sum_n w[n] * 2^( S[m][n] ),  S = (2*gamma*log2e*Xq).Xt^T
//
// R15: R14 (32x32x16 shape, -17% matrix time vs 16x16x32 per ubench) with the
// spill bug fixed. R14's VGPR=52 / 800MB FETCH came from RUNTIME-indexed
// register arrays: ch[g%3] and afrag[rt][(g&3)*4+q] forced ch AND the whole
// 128-reg afrag into scratch. Fix: named chA/chB ping-pong + outer loop
// stepped by 4 so buffer choice and within-tile chunk id are compile-time.
// RULE: register-array indices must be compile-time; rotate buffers by name,
// loop period = LCM(buffers, phases). Budget: afrag 128 + ch 32 + acc 32 +
// outacc 32 + misc ~ 240 <= 256 @ 2 waves/SIMD.
// Locked: bf16, 64 rows/wave, 512 blocks, regular loads (no global_load_lds:
// R1-R5 DMA bypassed L2), no per-step barriers (R9), w in LDS (R7).

#define MM 8192
#define NN 8192
#define DD 256
#define GAMMA (1.0f/256.0f)
#define LOG2E 1.44269504088896340736f
#define SCALE_A (2.0f*GAMMA*LOG2E)
#define NEG_G_LOG2E (-GAMMA*LOG2E)

#define NSPLIT 16
#define NPB (NN/NSPLIT)     // 512 cols per block
#define NT_PER (NPB/32)     // 16 column-tiles of 32
#define NCHUNK (NT_PER*4)   // 64 quarter-K chunks (4 k-steps each)

typedef __bf16 bf16x8 __attribute__((ext_vector_type(8)));
typedef float  f32x16 __attribute__((ext_vector_type(16)));

// ws: [0,4MB) A frag-linear (32-row tiles); [4MB,8MB) B frag-linear;
//     [8MB,+32K) w; [+32K] ea; [+64K] part[16][8192] f32
#define A_OFF  ((size_t)0)
#define B_OFF  ((size_t)4 << 20)
#define W_OFF  ((size_t)8 << 20)
#define EA_OFF (((size_t)8 << 20) + 32768)
#define PART_OFF (((size_t)8 << 20) + 65536)

__device__ __forceinline__ unsigned short f2bf(float f) {  // RNE f32->bf16
  union { float f; uint32_t u; } x; x.f = f;
  uint32_t u = x.u;
  u += 0x7FFFu + ((u >> 16) & 1u);
  return (unsigned short)(u >> 16);
}
__device__ __forceinline__ uint32_t pack2(float a, float b) {
  return (uint32_t)f2bf(a) | ((uint32_t)f2bf(b) << 16);
}

// 32-row/col tile t, k-step s (K=16 each), lane l: the 16 B at
// dst + t*16384 + s*1024 + l*16 hold row/col n = t*32+(l&31),
// k = s*16 + (l>>5)*8 .. +8 — mfma_32x32x16 A/B operand layout (shared
// k-convention on both operands, so k-permutation errors cancel).
__global__ __launch_bounds__(256) void prep_kernel(
    const float* __restrict__ Xq, const float* __restrict__ Xt,
    const float* __restrict__ alpha,
    char* __restrict__ Amat, char* __restrict__ Bmat,
    float* __restrict__ w, float* __restrict__ ea)
{
  const int lane = threadIdx.x & 63;
  const int gw = blockIdx.x * 4 + (threadIdx.x >> 6);  // 0..511
  const bool isA = gw < 256;
  const int t = isA ? gw : gw - 256;
  const float* __restrict__ src = isA ? Xq : Xt;
  char* __restrict__ dst = isA ? Amat : Bmat;
  const float sc = isA ? SCALE_A : 1.0f;
  const int r = t * 32 + (lane & 31);
  const int h = lane >> 5;
  float ss = 0.f;
#pragma unroll
  for (int s = 0; s < 16; ++s) {
    const float* p = src + (size_t)r * DD + s * 16 + h * 8;
    const float4 f0 = *(const float4*)p;
    const float4 f1 = *(const float4*)(p + 4);
    ss += f0.x*f0.x + f0.y*f0.y + f0.z*f0.z + f0.w*f0.w
        + f1.x*f1.x + f1.y*f1.y + f1.z*f1.z + f1.w*f1.w;
    uint4 pk;
    pk.x = pack2(f0.x * sc, f0.y * sc); pk.y = pack2(f0.z * sc, f0.w * sc);
    pk.z = pack2(f1.x * sc, f1.y * sc); pk.w = pack2(f1.z * sc, f1.w * sc);
    *(uint4*)(dst + (size_t)t * 16384 + s * 1024 + lane * 16) = pk;
  }
  ss += __shfl_xor(ss, 32, 64);   // combine the two k-halves of row r
  if (lane < 32) {
    if (isA) ea[r] = __builtin_amdgcn_exp2f(NEG_G_LOG2E * ss);
    else     w[r]  = alpha[r] * __builtin_amdgcn_exp2f(NEG_G_LOG2E * ss);
  }
}

__global__ __launch_bounds__(256, 2) void rbf_main(
    const char* __restrict__ Amat, const char* __restrict__ Bmat,
    const float* __restrict__ w, const float* __restrict__ ea,
    float* __restrict__ part)
{
  __shared__ float lds_w[NPB];   // 2 KB: the block's w slice (lgkm-only reads)
  const int tid  = threadIdx.x;
  const int wave = tid >> 6, lane = tid & 63;
  const int l32 = lane & 31, h = lane >> 5;

  // 512 blocks = 32 my x 16 nx; XCD b&7 gets 8 my x 8 nx
  const int b    = blockIdx.x;
  const int xcd  = b & 7, slot = b >> 3;             // slot 0..63
  const int my   = (xcd & 3) * 8 + (slot & 7);       // 0..31 (256 rows each)
  const int nx   = (xcd >> 2) * 8 + (slot >> 3);     // 0..15
  const int mt0    = my * 8 + wave * 2;              // 2 row-tiles of 32 = 64 rows/wave
  const int nt0    = nx * NT_PER;
  const int nbase0 = nx * NPB;

  // stage w slice to LDS (single barrier in the whole kernel)
  {
    const float2 wv2 = *(const float2*)(w + nbase0 + tid * 2);
    lds_w[tid * 2]     = wv2.x;
    lds_w[tid * 2 + 1] = wv2.y;
  }

  // A fragments register-resident for full K=256: 2 rt x 16 s x 4 = 128 regs
  bf16x8 afrag[2][16];
#pragma unroll
  for (int rt = 0; rt < 2; ++rt)
#pragma unroll
    for (int s = 0; s < 16; ++s) {
      union { uint4 u; bf16x8 v; } cv;
      cv.u = *(const uint4*)(Amat + (size_t)(mt0 + rt) * 16384 + s * 1024 + lane * 16);
      afrag[rt][s] = cv.v;
    }

  __syncthreads();   // lds_w ready

  float outacc[2][16];
#pragma unroll
  for (int rt = 0; rt < 2; ++rt)
#pragma unroll
    for (int i = 0; i < 16; ++i) outacc[rt][i] = 0.f;

  f32x16 acc[2];
  const f32x16 zero16 = {0,0,0,0,0,0,0,0,0,0,0,0,0,0,0,0};
  acc[0] = zero16; acc[1] = zero16;

  // B quarter-K chunks (4 k-steps = 16 regs), two NAMED ping-pong buffers
  uint4 chA[4], chB[4];
  auto loadChunk = [&](uint4* dst, int g) {       // g = global chunk id
    const char* base = Bmat + (size_t)(nt0 + (g >> 2)) * 16384
                            + (size_t)(g & 3) * 4096 + (size_t)lane * 16;
#pragma unroll
    for (int q = 0; q < 4; ++q)
      dst[q] = *(const uint4*)(base + q * 1024);
  };

  loadChunk(chA, 0);
  loadChunk(chB, 1);
  for (int g = 0; g < NCHUNK; g += 4) {   // 16 iterations; all reg indices static
#pragma unroll
    for (int cc = 0; cc < 4; ++cc) {      // cc = compile-time chunk-in-tile
      const uint4* buf = (cc & 1) ? chB : chA;
#pragma unroll
      for (int q = 0; q < 4; ++q) {
        const int s = cc * 4 + q;         // compile-time afrag index
        union { uint4 u; bf16x8 v; } cv; cv.u = buf[q];
        acc[0] = __builtin_amdgcn_mfma_f32_32x32x16_bf16(afrag[0][s], cv.v, acc[0], 0, 0, 0);
        acc[1] = __builtin_amdgcn_mfma_f32_32x32x16_bf16(afrag[1][s], cv.v, acc[1], 0, 0, 0);
      }
      // refill the just-consumed buffer, 2 chunks ahead (compile-time name)
      if (g + cc + 2 < NCHUNK) loadChunk((cc & 1) ? chB : chA, g + cc + 2);
    }
    { // epilogue for finished 32-col tile (measured m74 C/D map)
      const int ct = g >> 2;
      const float wv = lds_w[ct * 32 + l32];   // ds_read: lgkm only
#pragma unroll
      for (int rt = 0; rt < 2; ++rt) {
#pragma unroll
        for (int i = 0; i < 16; ++i)
          outacc[rt][i] += wv * __builtin_amdgcn_exp2f(acc[rt][i]);
        acc[rt] = zero16;
      }
    }
  }

  // reduce over the 32 columns (l32); C/D row = (i&3)+8*(i>>2)+4*h
#pragma unroll
  for (int rt = 0; rt < 2; ++rt)
#pragma unroll
    for (int i = 0; i < 16; ++i) {
      float v = outacc[rt][i];
      v += __shfl_xor(v, 1, 64);
      v += __shfl_xor(v, 2, 64);
      v += __shfl_xor(v, 4, 64);
      v += __shfl_xor(v, 8, 64);
      v += __shfl_xor(v, 16, 64);
      if (l32 == 0) {
        const int row = my * 256 + wave * 64 + rt * 32 + (i & 3) + 8 * (i >> 2) + 4 * h;
        part[(size_t)nx * MM + row] = ea[row] * v;
      }
    }
}

__global__ __launch_bounds__(256) void reduce_kernel(
    const float* __restrict__ part, float* __restrict__ out)
{
  const int row = blockIdx.x * 256 + threadIdx.x;
  float s = 0.f;
#pragma unroll
  for (int i = 0; i < NSPLIT; ++i) s += part[(size_t)i * MM + row];
  out[row] = s;
}

extern "C" void kernel_launch(void* const* d_in, const int* in_sizes, int n_in,
                              void* d_out, int out_size, void* d_ws, size_t ws_size,
                              hipStream_t stream) {
  const float* Xq    = (const float*)d_in[0];
  const float* Xt    = (const float*)d_in[1];
  const float* alpha = (const float*)d_in[2];
  float* out = (float*)d_out;
  char*  ws  = (char*)d_ws;

  char*  Amat = ws + A_OFF;
  char*  Bmat = ws + B_OFF;
  float* w    = (float*)(ws + W_OFF);
  float* ea   = (float*)(ws + EA_OFF);
  float* part = (float*)(ws + PART_OFF);

  hipLaunchKernelGGL(prep_kernel, dim3(128), dim3(256), 0, stream,
                     Xq, Xt, alpha, Amat, Bmat, w, ea);
  hipLaunchKernelGGL(rbf_main, dim3(512), dim3(256), 0, stream,
                     Amat, Bmat, w, ea, part);
  hipLaunchKernelGGL(reduce_kernel, dim3(MM / 256), dim3(256), 0, stream,
                     part, out);
}